// Round 23
// baseline (194.736 us; speedup 1.0000x reference)
//
#include <hip/hip_runtime.h>

// B=2, T=2048, C=2048, H=16, KH=4, D=128, rep=4

typedef __attribute__((ext_vector_type(8))) short bf16x8;
typedef __attribute__((ext_vector_type(4))) float f32x4;
typedef __attribute__((ext_vector_type(16))) float f32x16;

__device__ __forceinline__ unsigned short f2bf(float f) {
  union { float f; unsigned u; } v; v.f = f;
  unsigned u = v.u;
  u += 0x7fffu + ((u >> 16) & 1u);   // RNE
  return (unsigned short)(u >> 16);
}
__device__ __forceinline__ float bf2f(unsigned short h) {
  union { unsigned u; float f; } v; v.u = ((unsigned)h) << 16;
  return v.f;
}
__device__ __forceinline__ unsigned cvtpk_bf16(float lo, float hi) {
  unsigned r;
  asm("v_cvt_pk_bf16_f32 %0, %1, %2" : "=v"(r) : "v"(lo), "v"(hi));
  return r;  // low16 = bf16(lo), high16 = bf16(hi)
}

// global -> LDS async copy, 16B per lane. LDS dest must be wave-uniform;
// HW writes lane l at dest + 16*l. Source addr is per-lane.
__device__ __forceinline__ void gl_lds16(const void* g, void* l) {
  __builtin_amdgcn_global_load_lds(
      (const __attribute__((address_space(1))) unsigned int*)(unsigned long long)g,
      (__attribute__((address_space(3))) unsigned int*)(unsigned int)(unsigned long long)l,
      16, 0, 0);
}

// ---------------------------------------------------------------------------
// All fp32 -> bf16 casts in ONE launch: x -> xb, Wq|Wk|Wv -> Wcat, Wo -> Wob
__global__ void cvt_all(const float* __restrict__ x, const float* __restrict__ wq,
                        const float* __restrict__ wk, const float* __restrict__ wv,
                        const float* __restrict__ wo,
                        unsigned short* __restrict__ xb,
                        unsigned short* __restrict__ wcat,
                        unsigned short* __restrict__ wob) {
  const long nx = 2097152, nq = 1048576, nk = 262144;  // float4 units
  const long b1 = nx, b2 = nx + nq, b3 = b2 + nk, b4 = b3 + nk;
  const long tot = b4 + 1048576;
  long i = (long)blockIdx.x * blockDim.x + threadIdx.x;
  const long stride = (long)gridDim.x * blockDim.x;
  for (; i < tot; i += stride) {
    float4 vv; unsigned short* dst; long o;
    if (i < b1)      { vv = ((const float4*)x)[i];       dst = xb;   o = i; }
    else if (i < b2) { vv = ((const float4*)wq)[i - b1]; dst = wcat; o = i - b1; }
    else if (i < b3) { vv = ((const float4*)wk)[i - b2]; dst = wcat; o = (i - b2) + nq; }
    else if (i < b4) { vv = ((const float4*)wv)[i - b3]; dst = wcat; o = (i - b3) + nq + nk; }
    else             { vv = ((const float4*)wo)[i - b4]; dst = wob;  o = i - b4; }
    ushort4 u;
    u.x = f2bf(vv.x); u.y = f2bf(vv.y); u.z = f2bf(vv.z); u.w = f2bf(vv.w);
    ((ushort4*)dst)[o] = u;
  }
}

// ---------------------------------------------------------------------------
// 128x192 NT GEMM, 32x32x16 MFMA, bf16 out (qkv). R23: 256 threads (4 waves,
// 2Mx2N, wave tile 64x96 — identical per-wave math to R22's gemm384), LDS
// 80KB -> 2 blocks/CU, grid 32x16 = 512 = 2/CU. Rationale: R21 proved the
// tile-end vmcnt(0)+barrier drain is hidden by a CO-RESIDENT block's waves,
// not by deeper buffering; both GEMMs previously ran 1 block/CU.
__global__ __launch_bounds__(256)
void gemm192(const unsigned short* __restrict__ A,
             const unsigned short* __restrict__ Bm,
             unsigned short* __restrict__ Cp, int M, int N, int K) {
  __shared__ __align__(16) char ldsc[81920];   // 2 buf x (A 16KB | B 24KB)
  const int nbn = N / 192;   // 16
  int wg = blockIdx.x;
  { const int cpx = (int)gridDim.x >> 3;       // 512 -> bijective
    wg = (wg & 7) * cpx + (wg >> 3); }
  const int m0 = (wg / nbn) << 7, n0 = (wg % nbn) * 192;
  const int tid = threadIdx.x;
  const int lane = tid & 63, wid = tid >> 6;   // 4 waves
  const int l31 = lane & 31, hi = lane >> 5;
  const int wm = wid >> 1, wn = wid & 1;       // 2M x 2N
  const int swb = (lane & 7) << 4;             // rows 128B = 8 slots
  int aoff[2], boff[3];
  #pragma unroll
  for (int am = 0; am < 2; ++am) {
    const int r = wm * 64 + am * 32 + l31;
    aoff[am] = ((r >> 6) << 13) + ((r & 63) << 7);
  }
  #pragma unroll
  for (int bn = 0; bn < 3; ++bn) {
    const int r = wn * 96 + bn * 32 + l31;
    boff[bn] = 16384 + ((r >> 6) << 13) + ((r & 63) << 7);
  }
  // staging: chunk = 64 rows x 64k (8KB) in 2 segments of 32 rows (4KB/call).
  // scol swizzle is segment/chunk-invariant: all row bases == 0 mod 8.
  const int srow = tid >> 3;                   // 0..31
  const int scol = ((tid & 7) ^ (srow & 7)) << 3;
  const int sdst = wid << 10;
  const unsigned short* Ab = A + (size_t)(m0 + srow) * K + scol;
  const unsigned short* Bb = Bm + (size_t)(n0 + srow) * K + scol;
  const int NT = K >> 6;
  f32x16 acc[2][3] = {};

  auto stage = [&](size_t kk, int buf) {
    char* dst = ldsc + buf * 40960;
    #pragma unroll
    for (int c = 0; c < 2; ++c)      // A chunks (rows 64c..64c+63)
      #pragma unroll
      for (int s = 0; s < 2; ++s)
        gl_lds16(Ab + (size_t)(c * 64 + s * 32) * K + kk,
                 dst + c * 8192 + s * 4096 + sdst);
    #pragma unroll
    for (int c = 0; c < 3; ++c)      // B chunks
      #pragma unroll
      for (int s = 0; s < 2; ++s)
        gl_lds16(Bb + (size_t)(c * 64 + s * 32) * K + kk,
                 dst + 16384 + c * 8192 + s * 4096 + sdst);
  };

  stage(0, 0);
  asm volatile("s_waitcnt vmcnt(0)" ::: "memory");
  __builtin_amdgcn_s_barrier();

  for (int t = 0; t < NT; ++t) {
    const int cb = (t & 1) * 40960;
    const bool pf = (t + 1) < NT;
    if (pf) stage((size_t)(t + 1) << 6, (t & 1) ^ 1);
    __builtin_amdgcn_s_setprio(1);
    #pragma unroll
    for (int half = 0; half < 2; ++half) {
      bf16x8 af[2][2], bg[3][2];
      #pragma unroll
      for (int am = 0; am < 2; ++am)
        #pragma unroll
        for (int tt = 0; tt < 2; ++tt)
          af[am][tt] = *(const bf16x8*)(ldsc + cb + aoff[am] +
              ((((half * 2 + tt) << 5) + (hi << 4)) ^ swb));
      #pragma unroll
      for (int bn = 0; bn < 3; ++bn)
        #pragma unroll
        for (int tt = 0; tt < 2; ++tt)
          bg[bn][tt] = *(const bf16x8*)(ldsc + cb + boff[bn] +
              ((((half * 2 + tt) << 5) + (hi << 4)) ^ swb));
      #pragma unroll
      for (int am = 0; am < 2; ++am)
        #pragma unroll
        for (int bn = 0; bn < 3; ++bn)
          #pragma unroll
          for (int tt = 0; tt < 2; ++tt)
            acc[am][bn] = __builtin_amdgcn_mfma_f32_32x32x16_bf16(
                af[am][tt], bg[bn][tt], acc[am][bn], 0, 0, 0);
    }
    __builtin_amdgcn_s_setprio(0);
    asm volatile("s_waitcnt vmcnt(0)" ::: "memory");
    __builtin_amdgcn_s_barrier();
  }
  #pragma unroll
  for (int am = 0; am < 2; ++am) {
    const int mrowb = m0 + wm * 64 + am * 32 + (hi << 2);
    #pragma unroll
    for (int bn = 0; bn < 3; ++bn) {
      const int ncol = n0 + wn * 96 + bn * 32 + l31;
      #pragma unroll
      for (int qd = 0; qd < 4; ++qd)
        #pragma unroll
        for (int i = 0; i < 4; ++i)
          Cp[(size_t)(mrowb + 8 * qd + i) * N + ncol] = f2bf(acc[am][bn][qd * 4 + i]);
    }
  }
}

// ---------------------------------------------------------------------------
// 128x128 NT GEMM, 32x32x16 MFMA, fp32 out (out-proj). 256 threads (4 waves,
// 2Mx2N, wave tile 64x64), LDS 64KB -> 2 blocks/CU, grid 32x16 = 512 = 2/CU.
__global__ __launch_bounds__(256)
void gemm128b(const unsigned short* __restrict__ A,
              const unsigned short* __restrict__ Bm,
              float* __restrict__ Cp, int M, int N, int K) {
  __shared__ __align__(16) char ldsc[65536];   // 2 buf x (A 16KB | B 16KB)
  const int nbn = N >> 7;    // 16
  int wg = blockIdx.x;
  { const int cpx = (int)gridDim.x >> 3;
    wg = (wg & 7) * cpx + (wg >> 3); }
  const int m0 = (wg / nbn) << 7, n0 = (wg % nbn) << 7;
  const int tid = threadIdx.x;
  const int lane = tid & 63, wid = tid >> 6;
  const int l31 = lane & 31, hi = lane >> 5;
  const int wm = wid >> 1, wn = wid & 1;       // 2M x 2N
  const int swb = (lane & 7) << 4;
  int aoff[2], boff[2];
  #pragma unroll
  for (int am = 0; am < 2; ++am) {
    const int r = wm * 64 + am * 32 + l31;
    aoff[am] = ((r >> 6) << 13) + ((r & 63) << 7);
  }
  #pragma unroll
  for (int bn = 0; bn < 2; ++bn) {
    const int r = wn * 64 + bn * 32 + l31;
    boff[bn] = 16384 + ((r >> 6) << 13) + ((r & 63) << 7);
  }
  const int srow = tid >> 3;
  const int scol = ((tid & 7) ^ (srow & 7)) << 3;
  const int sdst = wid << 10;
  const unsigned short* Ab = A + (size_t)(m0 + srow) * K + scol;
  const unsigned short* Bb = Bm + (size_t)(n0 + srow) * K + scol;
  const int NT = K >> 6;
  f32x16 acc[2][2] = {};

  auto stage = [&](size_t kk, int buf) {
    char* dst = ldsc + buf * 32768;
    #pragma unroll
    for (int c = 0; c < 2; ++c)
      #pragma unroll
      for (int s = 0; s < 2; ++s)
        gl_lds16(Ab + (size_t)(c * 64 + s * 32) * K + kk,
                 dst + c * 8192 + s * 4096 + sdst);
    #pragma unroll
    for (int c = 0; c < 2; ++c)
      #pragma unroll
      for (int s = 0; s < 2; ++s)
        gl_lds16(Bb + (size_t)(c * 64 + s * 32) * K + kk,
                 dst + 16384 + c * 8192 + s * 4096 + sdst);
  };

  stage(0, 0);
  asm volatile("s_waitcnt vmcnt(0)" ::: "memory");
  __builtin_amdgcn_s_barrier();

  for (int t = 0; t < NT; ++t) {
    const int cb = (t & 1) * 32768;
    const bool pf = (t + 1) < NT;
    if (pf) stage((size_t)(t + 1) << 6, (t & 1) ^ 1);
    __builtin_amdgcn_s_setprio(1);
    #pragma unroll
    for (int half = 0; half < 2; ++half) {
      bf16x8 af[2][2], bg[2][2];
      #pragma unroll
      for (int am = 0; am < 2; ++am)
        #pragma unroll
        for (int tt = 0; tt < 2; ++tt)
          af[am][tt] = *(const bf16x8*)(ldsc + cb + aoff[am] +
              ((((half * 2 + tt) << 5) + (hi << 4)) ^ swb));
      #pragma unroll
      for (int bn = 0; bn < 2; ++bn)
        #pragma unroll
        for (int tt = 0; tt < 2; ++tt)
          bg[bn][tt] = *(const bf16x8*)(ldsc + cb + boff[bn] +
              ((((half * 2 + tt) << 5) + (hi << 4)) ^ swb));
      #pragma unroll
      for (int am = 0; am < 2; ++am)
        #pragma unroll
        for (int bn = 0; bn < 2; ++bn)
          #pragma unroll
          for (int tt = 0; tt < 2; ++tt)
            acc[am][bn] = __builtin_amdgcn_mfma_f32_32x32x16_bf16(
                af[am][tt], bg[bn][tt], acc[am][bn], 0, 0, 0);
    }
    __builtin_amdgcn_s_setprio(0);
    asm volatile("s_waitcnt vmcnt(0)" ::: "memory");
    __builtin_amdgcn_s_barrier();
  }
  #pragma unroll
  for (int am = 0; am < 2; ++am) {
    const int mrowb = m0 + wm * 64 + am * 32 + (hi << 2);
    #pragma unroll
    for (int bn = 0; bn < 2; ++bn) {
      const int ncol = n0 + wn * 64 + bn * 32 + l31;
      #pragma unroll
      for (int qd = 0; qd < 4; ++qd)
        #pragma unroll
        for (int i = 0; i < 4; ++i)
          Cp[(size_t)(mrowb + 8 * qd + i) * N + ncol] = acc[am][bn][qd * 4 + i];
    }
  }
}

// ---------------------------------------------------------------------------
// Fused prep: blocks [0, 20480) = RMSNorm+RoPE (wave-per-row);
// blocks [20480, 20992) = V transpose + col-perm.  One launch, 256 threads.
__global__ __launch_bounds__(256)
void prep(const unsigned short* __restrict__ qkv,
          const float* __restrict__ cosb, const float* __restrict__ sinb,
          const float* __restrict__ qw, const float* __restrict__ kw,
          unsigned short* __restrict__ Qb, unsigned short* __restrict__ Kb,
          unsigned short* __restrict__ Vt) {
  __shared__ unsigned short tile[64][68];
  if (blockIdx.x < 20480) {
    const int wv = threadIdx.x >> 6, l = threadIdx.x & 63;
    const int rr = blockIdx.x * 4 + wv;
    const int hh = rr % 20, bt = rr / 20;
    const bool isq = hh < 16;
    const ushort2 u = *(const ushort2*)(qkv + (size_t)bt * 3072 + (hh << 7) + 2 * l);
    const float v0 = bf2f(u.x), v1 = bf2f(u.y);
    float ss = v0 * v0 + v1 * v1;
    #pragma unroll
    for (int off = 1; off < 64; off <<= 1) ss += __shfl_xor(ss, off);
    const float rms = rsqrtf(ss * (1.0f / 128.0f) + 1e-6f);
    const float* w = isq ? qw : kw;
    const float2 w2 = *(const float2*)(w + 2 * l);
    const float n0 = v0 * rms * w2.x, n1 = v1 * rms * w2.y;
    const float sx0 = __shfl_xor(n0, 32), sx1 = __shfl_xor(n1, 32);
    const float p0 = (l < 32) ? -sx0 : sx0;
    const float p1 = (l < 32) ? -sx1 : sx1;
    const float2 c2 = *(const float2*)(cosb + (size_t)bt * 128 + 2 * l);
    const float2 s2 = *(const float2*)(sinb + (size_t)bt * 128 + 2 * l);
    const float qsc = isq ? 0.08838834764831845f : 1.0f;
    ushort2 o;
    o.x = f2bf((n0 * c2.x + p0 * s2.x) * qsc);
    o.y = f2bf((n1 * c2.y + p1 * s2.y) * qsc);
    const int b = bt >> 11, t = bt & 2047;
    if (isq)
      *(ushort2*)(Qb + (((size_t)(b * 16 + hh) * 2048 + t) << 7) + 2 * l) = o;
    else
      *(ushort2*)(Kb + (((size_t)(b * 4 + (hh - 16)) * 2048 + t) << 7) + 2 * l) = o;
  } else {
    const int vb = blockIdx.x - 20480;      // 512 blocks: (bh 8, t0 32, d0 2)
    const int bh = vb >> 6, rest = vb & 63;
    const int b = bh >> 2, h = bh & 3;
    const int t0 = (rest >> 1) << 6, d0 = (rest & 1) << 6;
    const int tid = threadIdx.x;
    #pragma unroll
    for (int p = 0; p < 4; ++p) {
      const int idx = ((p << 8) + tid) << 2;
      const int r = idx >> 6, c = idx & 63;
      *(ushort4*)(&tile[r][c]) = *(const ushort4*)(
          qkv + (size_t)(b * 2048 + t0 + r) * 3072 + 2560 + (h << 7) + d0 + c);
    }
    __syncthreads();
    unsigned short* vbase = Vt + (size_t)((b * 4 + h) * 128 + d0) * 2048 + t0;
    #pragma unroll
    for (int p = 0; p < 4; ++p) {
      const int idx = ((p << 8) + tid) << 2;
      const int d = idx >> 6, tq = idx & 63;
      const int tin = (tq & 48) | ((tq & 8) >> 1) | ((tq & 4) << 1);
      ushort4 u;
      u.x = tile[tin + 0][d];
      u.y = tile[tin + 1][d];
      u.z = tile[tin + 2][d];
      u.w = tile[tin + 3][d];
      *(ushort4*)(vbase + ((size_t)d << 11) + tq) = u;
    }
  }
}

// ---------------------------------------------------------------------------
// Causal GQA flash attention (R20 exact, proven 63.0us): 32x32x16 MFMA,
// 8-wave even/odd kv-parity, adjacent tile pairing, balanced p relabel,
// 16-slot K swizzle, 2-barrier 2-block/CU.
__global__ __launch_bounds__(512)
void attn_fwd(const unsigned short* __restrict__ Qb,  // (B,H,T,D), pre-scaled
              const unsigned short* __restrict__ Kb,  // (B,KH,T,D)
              const unsigned short* __restrict__ Vt,  // (B,KH,D,T'), col-permuted
              unsigned short* __restrict__ Y) {       // (B,T,H,D)
  __shared__ __align__(16) char L[65536];  // [g][K 16KB | V 16KB]
  const int bh = blockIdx.x;
  const int b = bh >> 4, h = bh & 15, hk = h >> 2;
  const int py = blockIdx.y;
  const int p = (py < 8) ? py : 23 - py;   // balanced relabel (bijective 0..15)
  const int tid = threadIdx.x;
  const int lane = tid & 63, wid = tid >> 6;
  const int g = wid >> 2;            // kv parity group
  const int wid2 = wid & 3;
  const int j = wid2 >> 1;           // tile slot
  const int qt = (p << 1) + j;       // adjacent pairing
  const int sub = (wid2 & 1) << 5;   // row half within tile
  const int l31 = lane & 31, hi = lane >> 5;
  const int swbK = (lane & 15) << 4;   // K: 16 slots (256B rows)
  const int swbV = (lane & 7) << 4;    // V: 8 slots (128B rows)
  char* KsC = L + g * 32768;
  char* VsC = KsC + 16384;
  const unsigned short* Kp = Kb + (size_t)(b * 4 + hk) * 2048 * 128;
  const unsigned short* Vp = Vt + (size_t)(b * 4 + hk) * 128 * 2048;
  const int qg = qt * 64 + sub + l31;   // this lane's q-row
  const unsigned short* Qp = Qb + (size_t)((b * 16 + h) * 2048 + qg) * 128;
  bf16x8 aq[8];
  #pragma unroll
  for (int ks = 0; ks < 8; ++ks)
    aq[ks] = *(const bf16x8*)(Qp + (ks << 4) + (hi << 3));
  float m_i = -1e30f, l_i = 0.f;
  f32x16 acc[4] = {};   // dblk 0..3; d = 32*dblk + (r&3)+8*(r>>2)+4*hi
  const int kr_in = (lane >> 4), kcb = (lane & 15) << 4;   // K chunk: 4 rows x 256B
  const int vr_in = (lane >> 3), vcb = (lane & 7) << 4;    // V chunk: 8 rows x 128B
  const int nkb = (p << 1) + 2;       // stage exactly tiles 0..2p+1
  const int nit = (nkb + 1) >> 1;     // = p+1

  for (int it = 0; it < nit; ++it) {
    const int kb = 2 * it + g;
    const bool act = kb < nkb;          // wave-uniform (always true here)
    if (act) {
      const int k0 = kb << 6;
      #pragma unroll
      for (int i = 0; i < 4; ++i) {
        const int c = (wid2 << 2) + i;
        { const int r = (c << 2) + kr_in;
          const int sw = kcb ^ ((r & 15) << 4);   // 16-slot involution
          gl_lds16(Kp + (size_t)(k0 + r) * 128 + (sw >> 1), KsC + (c << 10)); }
        { const int r = (c << 3) + vr_in;
          const int sw = vcb ^ ((r & 7) << 4);
          gl_lds16(Vp + (size_t)r * 2048 + k0 + (sw >> 1), VsC + (c << 10)); }
      }
    }
    __syncthreads();
    if (act && kb <= qt) {
      const int k0 = kb << 6;
      f32x16 s[2] = {};
      __builtin_amdgcn_s_setprio(1);
      #pragma unroll
      for (int sblk = 0; sblk < 2; ++sblk) {
        const int row = (sblk << 5) + l31;
        #pragma unroll
        for (int ks = 0; ks < 8; ++ks) {
          const bf16x8 bk = *(const bf16x8*)(
              KsC + (row << 8) + (((ks << 5) + (hi << 4)) ^ swbK));
          s[sblk] = __builtin_amdgcn_mfma_f32_32x32x16_bf16(bk, aq[ks], s[sblk], 0, 0, 0);
        }
      }
      __builtin_amdgcn_s_setprio(0);
      if (kb == qt) {   // causal mask, diag block only
        #pragma unroll
        for (int sblk = 0; sblk < 2; ++sblk)
          #pragma unroll
          for (int r = 0; r < 16; ++r) {
            const int kv = k0 + (sblk << 5) + (r & 3) + ((r >> 2) << 3) + (hi << 2);
            if (kv > qg) s[sblk][r] = -1e30f;
          }
      }
      float mx = s[0][0];
      #pragma unroll
      for (int sblk = 0; sblk < 2; ++sblk)
        #pragma unroll
        for (int r = 0; r < 16; ++r) mx = fmaxf(mx, s[sblk][r]);
      mx = fmaxf(mx, __shfl_xor(mx, 32));
      if (!__all(mx <= m_i + 8.0f)) {   // defer-max (THR=8)
        const float mn = fmaxf(m_i, mx);
        const float r = __expf(m_i - mn);
        m_i = mn;
        l_i *= r;
        #pragma unroll
        for (int d = 0; d < 4; ++d)
          #pragma unroll
          for (int i = 0; i < 16; ++i) acc[d][i] *= r;
      }
      float se = 0.f;
      unsigned pk[16];
      #pragma unroll
      for (int t2 = 0; t2 < 16; ++t2) {
        const int f0 = 2 * t2, f1 = 2 * t2 + 1;
        const float e0 = __expf(s[f0 >> 4][f0 & 15] - m_i);
        const float e1 = __expf(s[f1 >> 4][f1 & 15] - m_i);
        se += e0 + e1;
        pk[t2] = cvtpk_bf16(e0, e1);
      }
      se += __shfl_xor(se, 32);
      l_i += se;
      __builtin_amdgcn_s_setprio(1);
      #pragma unroll
      for (int dblk = 0; dblk < 4; ++dblk) {
        const int row = (dblk << 5) + l31;
        #pragma unroll
        for (int cp = 0; cp < 4; ++cp) {
          const bf16x8 va = *(const bf16x8*)(
              VsC + (row << 7) + (((cp << 5) + (hi << 4)) ^ swbV));
          union { unsigned u[4]; bf16x8 v; } pb;
          pb.u[0] = pk[cp * 4 + 0]; pb.u[1] = pk[cp * 4 + 1];
          pb.u[2] = pk[cp * 4 + 2]; pb.u[3] = pk[cp * 4 + 3];
          acc[dblk] = __builtin_amdgcn_mfma_f32_32x32x16_bf16(va, pb.v, acc[dblk], 0, 0, 0);
        }
      }
      __builtin_amdgcn_s_setprio(0);
    }
    __syncthreads();
  }

  // parity combine: round jj — g=1 waves of tile jj dump, g=0 merge+write.
  float* cb = (float*)L;
  #pragma unroll
  for (int jj = 0; jj < 2; ++jj) {
    const int base = (((wid2 & 1) << 6) + lane) * 66;
    if (g == 1 && j == jj) {
      #pragma unroll
      for (int d = 0; d < 4; ++d)
        #pragma unroll
        for (int i = 0; i < 16; ++i) cb[base + d * 16 + i] = acc[d][i];
      cb[base + 64] = m_i;
      cb[base + 65] = l_i;
    }
    __syncthreads();
    if (g == 0 && j == jj) {
      const float m1 = cb[base + 64], l1v = cb[base + 65];
      const float m = fmaxf(m_i, m1);
      const float e0 = __expf(m_i - m), e1 = __expf(m1 - m);
      const float inv = 1.0f / (l_i * e0 + l1v * e1);
      unsigned short* Yp = Y + (((size_t)b * 2048 + qg) * 16 + h) * 128;
      #pragma unroll
      for (int dblk = 0; dblk < 4; ++dblk) {
        #pragma unroll
        for (int qd = 0; qd < 4; ++qd) {
          ushort4 o;
          o.x = f2bf((acc[dblk][qd * 4 + 0] * e0 + cb[base + dblk * 16 + qd * 4 + 0] * e1) * inv);
          o.y = f2bf((acc[dblk][qd * 4 + 1] * e0 + cb[base + dblk * 16 + qd * 4 + 1] * e1) * inv);
          o.z = f2bf((acc[dblk][qd * 4 + 2] * e0 + cb[base + dblk * 16 + qd * 4 + 2] * e1) * inv);
          o.w = f2bf((acc[dblk][qd * 4 + 3] * e0 + cb[base + dblk * 16 + qd * 4 + 3] * e1) * inv);
          *(ushort4*)(Yp + (dblk << 5) + (qd << 3) + (hi << 2)) = o;
        }
      }
    }
    __syncthreads();
  }
}

// ---------------------------------------------------------------------------
extern "C" void kernel_launch(void* const* d_in, const int* in_sizes, int n_in,
                              void* d_out, int out_size, void* d_ws, size_t ws_size,
                              hipStream_t stream) {
  const float* x    = (const float*)d_in[0];
  const float* cosb = (const float*)d_in[1];
  const float* sinb = (const float*)d_in[2];
  const float* Wq   = (const float*)d_in[3];
  const float* Wk   = (const float*)d_in[4];
  const float* Wv   = (const float*)d_in[5];
  const float* Wo   = (const float*)d_in[6];
  const float* qw   = (const float*)d_in[7];
  const float* kw   = (const float*)d_in[8];
  char* ws = (char*)d_ws;
  unsigned short* xb   = (unsigned short*)(ws);                       // 16MB x bf16, later reused as Y
  unsigned short* Wcat = (unsigned short*)(ws + (16ull << 20));       // 12MB [Wq;Wk;Wv] bf16
  unsigned short* Wob  = (unsigned short*)(ws + (28ull << 20));       // 8MB Wo bf16
  unsigned short* qkv  = (unsigned short*)(ws + (36ull << 20));       // 24MB (4096,3072) bf16
  unsigned short* Qb   = (unsigned short*)(ws + (60ull << 20));       // 16MB (B,H,T,D)
  unsigned short* Kb   = (unsigned short*)(ws + (76ull << 20));       // 4MB  (B,KH,T,D)
  unsigned short* Vt   = (unsigned short*)(ws + (80ull << 20));       // 4MB  (B,KH,D,T'), col-permuted

  // all input casts in one launch
  cvt_all<<<2048, 256, 0, stream>>>(x, Wq, Wk, Wv, Wo, xb, Wcat, Wob);

  // qkv = x @ [Wq;Wk;Wv]^T   (M=4096, N=3072, K=2048): 32x16 = 512 = 2/CU
  gemm192<<<512, 256, 0, stream>>>(xb, Wcat, qkv, 4096, 3072, 2048);
  // RMSNorm+RoPE (20480 blocks) + V-transpose (512 blocks) in one launch
  prep<<<20992, 256, 0, stream>>>(qkv, cosb, sinb, qw, kw, Qb, Kb, Vt);
  // attention -> Y (reuses xb); balanced p relabel, even/odd kv parity
  attn_fwd<<<dim3(32, 16), 512, 0, stream>>>(Qb, Kb, Vt, xb);
  // out = Y @ Wo^T  (M=4096, N=2048, K=2048): 32x16 = 512 = 2/CU
  gemm128b<<<512, 256, 0, stream>>>(xb, Wob, (float*)d_out, 4096, 2048, 2048);
}

// Round 24
// 189.924 us; speedup vs baseline: 1.0253x; 1.0253x over previous
//
#include <hip/hip_runtime.h>

// B=2, T=2048, C=2048, H=16, KH=4, D=128, rep=4
// R24 = exact revert to R22 config (session best, 190.1us):
//   cvt_all + gemm384 (1/CU) + prep + attn_fwd (R20) + gemm128n (1/CU).
// R23's 2-block/CU GEMM split regressed +4.6us: identical lockstep blocks
// contend for the same pipes; co-residency only pays for heterogeneous
// blocks (attn). All components now at verified local optima.

typedef __attribute__((ext_vector_type(8))) short bf16x8;
typedef __attribute__((ext_vector_type(4))) float f32x4;
typedef __attribute__((ext_vector_type(16))) float f32x16;

__device__ __forceinline__ unsigned short f2bf(float f) {
  union { float f; unsigned u; } v; v.f = f;
  unsigned u = v.u;
  u += 0x7fffu + ((u >> 16) & 1u);   // RNE
  return (unsigned short)(u >> 16);
}
__device__ __forceinline__ float bf2f(unsigned short h) {
  union { unsigned u; float f; } v; v.u = ((unsigned)h) << 16;
  return v.f;
}
__device__ __forceinline__ unsigned cvtpk_bf16(float lo, float hi) {
  unsigned r;
  asm("v_cvt_pk_bf16_f32 %0, %1, %2" : "=v"(r) : "v"(lo), "v"(hi));
  return r;  // low16 = bf16(lo), high16 = bf16(hi)
}

// global -> LDS async copy, 16B per lane. LDS dest must be wave-uniform;
// HW writes lane l at dest + 16*l. Source addr is per-lane.
__device__ __forceinline__ void gl_lds16(const void* g, void* l) {
  __builtin_amdgcn_global_load_lds(
      (const __attribute__((address_space(1))) unsigned int*)(unsigned long long)g,
      (__attribute__((address_space(3))) unsigned int*)(unsigned int)(unsigned long long)l,
      16, 0, 0);
}

// ---------------------------------------------------------------------------
// All fp32 -> bf16 casts in ONE launch: x -> xb, Wq|Wk|Wv -> Wcat, Wo -> Wob
__global__ void cvt_all(const float* __restrict__ x, const float* __restrict__ wq,
                        const float* __restrict__ wk, const float* __restrict__ wv,
                        const float* __restrict__ wo,
                        unsigned short* __restrict__ xb,
                        unsigned short* __restrict__ wcat,
                        unsigned short* __restrict__ wob) {
  const long nx = 2097152, nq = 1048576, nk = 262144;  // float4 units
  const long b1 = nx, b2 = nx + nq, b3 = b2 + nk, b4 = b3 + nk;
  const long tot = b4 + 1048576;
  long i = (long)blockIdx.x * blockDim.x + threadIdx.x;
  const long stride = (long)gridDim.x * blockDim.x;
  for (; i < tot; i += stride) {
    float4 vv; unsigned short* dst; long o;
    if (i < b1)      { vv = ((const float4*)x)[i];       dst = xb;   o = i; }
    else if (i < b2) { vv = ((const float4*)wq)[i - b1]; dst = wcat; o = i - b1; }
    else if (i < b3) { vv = ((const float4*)wk)[i - b2]; dst = wcat; o = (i - b2) + nq; }
    else if (i < b4) { vv = ((const float4*)wv)[i - b3]; dst = wcat; o = (i - b3) + nq + nk; }
    else             { vv = ((const float4*)wo)[i - b4]; dst = wob;  o = i - b4; }
    ushort4 u;
    u.x = f2bf(vv.x); u.y = f2bf(vv.y); u.z = f2bf(vv.z); u.w = f2bf(vv.w);
    ((ushort4*)dst)[o] = u;
  }
}

// ---------------------------------------------------------------------------
// 128x384 NT GEMM, 32x32x16 MFMA, bf16 out (qkv). 256 blocks = 1/CU.
__global__ __launch_bounds__(512, 2)
void gemm384(const unsigned short* __restrict__ A,
             const unsigned short* __restrict__ Bm,
             unsigned short* __restrict__ Cp, int M, int N, int K) {
  __shared__ __align__(16) char ldsc[131072];
  const int nbn = N / 384;   // 8
  int wg = blockIdx.x;
  { const int cpx = (int)gridDim.x >> 3;
    wg = (wg & 7) * cpx + (wg >> 3); }
  const int m0 = (wg / nbn) << 7, n0 = (wg % nbn) * 384;
  const int tid = threadIdx.x;
  const int lane = tid & 63, wid = tid >> 6;
  const int l31 = lane & 31, hi = lane >> 5;
  const int wm = wid >> 2, wn = wid & 3;  // 2M x 4N
  const int swb = (lane & 7) << 4;
  int aoff[2], boff[3];
  #pragma unroll
  for (int am = 0; am < 2; ++am) {
    const int r = wm * 64 + am * 32 + l31;
    aoff[am] = ((r >> 6) << 13) + ((r & 63) << 7);
  }
  #pragma unroll
  for (int bn = 0; bn < 3; ++bn) {
    const int r = wn * 96 + bn * 32 + l31;
    boff[bn] = 16384 + ((r >> 6) << 13) + ((r & 63) << 7);
  }
  const int srowL = tid >> 3;
  const int scol = ((tid & 7) ^ (srowL & 7)) << 3;
  const unsigned short* Asrc = A + (size_t)(m0 + srowL) * K + scol;
  const unsigned short* Bsrc = Bm + (size_t)(n0 + srowL) * K + scol;
  const int sdst = wid << 10;
  const int NT = K >> 6;
  f32x16 acc[2][3] = {};
  gl_lds16(Asrc, ldsc + sdst);
  gl_lds16(Asrc + (size_t)64 * K, ldsc + 8192 + sdst);
  #pragma unroll
  for (int c = 0; c < 6; ++c)
    gl_lds16(Bsrc + (size_t)(64 * c) * K, ldsc + 16384 + c * 8192 + sdst);
  asm volatile("s_waitcnt vmcnt(0)" ::: "memory");
  __builtin_amdgcn_s_barrier();

  for (int t = 0; t < NT; ++t) {
    const int curb = (t & 1) << 16;
    const int nxtb = curb ^ 65536;
    const size_t kn = (size_t)(t + 1) << 6;
    const bool pf = (t + 1) < NT;
    if (pf) {
      gl_lds16(Asrc + kn, ldsc + nxtb + sdst);
      gl_lds16(Asrc + (size_t)64 * K + kn, ldsc + nxtb + 8192 + sdst);
      #pragma unroll
      for (int c = 0; c < 6; ++c)
        gl_lds16(Bsrc + (size_t)(64 * c) * K + kn,
                 ldsc + nxtb + 16384 + c * 8192 + sdst);
    }
    __builtin_amdgcn_s_setprio(1);
    #pragma unroll
    for (int half = 0; half < 2; ++half) {
      bf16x8 af[2][2], bg[3][2];
      #pragma unroll
      for (int am = 0; am < 2; ++am)
        #pragma unroll
        for (int tt = 0; tt < 2; ++tt)
          af[am][tt] = *(const bf16x8*)(ldsc + curb + aoff[am] +
              ((((half * 2 + tt) << 5) + (hi << 4)) ^ swb));
      #pragma unroll
      for (int bn = 0; bn < 3; ++bn)
        #pragma unroll
        for (int tt = 0; tt < 2; ++tt)
          bg[bn][tt] = *(const bf16x8*)(ldsc + curb + boff[bn] +
              ((((half * 2 + tt) << 5) + (hi << 4)) ^ swb));
      #pragma unroll
      for (int am = 0; am < 2; ++am)
        #pragma unroll
        for (int bn = 0; bn < 3; ++bn)
          #pragma unroll
          for (int tt = 0; tt < 2; ++tt)
            acc[am][bn] = __builtin_amdgcn_mfma_f32_32x32x16_bf16(
                af[am][tt], bg[bn][tt], acc[am][bn], 0, 0, 0);
    }
    __builtin_amdgcn_s_setprio(0);
    asm volatile("s_waitcnt vmcnt(0)" ::: "memory");
    __builtin_amdgcn_s_barrier();
  }
  #pragma unroll
  for (int am = 0; am < 2; ++am) {
    const int mrowb = m0 + wm * 64 + am * 32 + (hi << 2);
    #pragma unroll
    for (int bn = 0; bn < 3; ++bn) {
      const int ncol = n0 + wn * 96 + bn * 32 + l31;
      #pragma unroll
      for (int qd = 0; qd < 4; ++qd)
        #pragma unroll
        for (int i = 0; i < 4; ++i)
          Cp[(size_t)(mrowb + 8 * qd + i) * N + ncol] = f2bf(acc[am][bn][qd * 4 + i]);
    }
  }
}

// ---------------------------------------------------------------------------
// 128x256 NT GEMM, 32x32x16 MFMA, fp32 out (out-proj). 256 blocks = 1/CU.
__global__ __launch_bounds__(512, 2)
void gemm128n(const unsigned short* __restrict__ A,
              const unsigned short* __restrict__ Bm,
              float* __restrict__ Cp, int M, int N, int K) {
  __shared__ __align__(16) char ldsc[98304];
  const int nbn = N >> 8;
  int wg = blockIdx.x;
  { const int cpx = (int)gridDim.x >> 3;
    wg = (wg & 7) * cpx + (wg >> 3); }
  const int m0 = (wg / nbn) << 7, n0 = (wg % nbn) << 8;
  const int tid = threadIdx.x;
  const int lane = tid & 63, wid = tid >> 6;
  const int l31 = lane & 31, hi = lane >> 5;
  const int wm = wid >> 2, wn = wid & 3;  // 2M x 4N
  const int swb = (lane & 7) << 4;
  int aoff[2], boff[2];
  #pragma unroll
  for (int am = 0; am < 2; ++am) {
    const int r = wm * 64 + am * 32 + l31;
    aoff[am] = ((r >> 6) << 13) + ((r & 63) << 7);
  }
  #pragma unroll
  for (int bn = 0; bn < 2; ++bn) {
    const int r = wn * 64 + bn * 32 + l31;
    boff[bn] = 16384 + ((r >> 6) << 13) + ((r & 63) << 7);
  }
  const int srowL = tid >> 3;
  const int scol = ((tid & 7) ^ (srowL & 7)) << 3;
  const unsigned short* Asrc = A + (size_t)(m0 + srowL) * K + scol;
  const unsigned short* Bsrc = Bm + (size_t)(n0 + srowL) * K + scol;
  const int sdst = wid << 10;
  const int NT = K >> 6;
  f32x16 acc[2][2] = {};
  gl_lds16(Asrc, ldsc + sdst);
  gl_lds16(Asrc + (size_t)64 * K, ldsc + 8192 + sdst);
  #pragma unroll
  for (int c = 0; c < 4; ++c)
    gl_lds16(Bsrc + (size_t)(64 * c) * K, ldsc + 16384 + c * 8192 + sdst);
  asm volatile("s_waitcnt vmcnt(0)" ::: "memory");
  __builtin_amdgcn_s_barrier();

  for (int t = 0; t < NT; ++t) {
    const int curb = (t & 1) ? 49152 : 0;
    const int nxtb = 49152 - curb;
    const size_t kn = (size_t)(t + 1) << 6;
    const bool pf = (t + 1) < NT;
    if (pf) {
      gl_lds16(Asrc + kn, ldsc + nxtb + sdst);
      gl_lds16(Asrc + (size_t)64 * K + kn, ldsc + nxtb + 8192 + sdst);
      #pragma unroll
      for (int c = 0; c < 4; ++c)
        gl_lds16(Bsrc + (size_t)(64 * c) * K + kn,
                 ldsc + nxtb + 16384 + c * 8192 + sdst);
    }
    __builtin_amdgcn_s_setprio(1);
    #pragma unroll
    for (int half = 0; half < 2; ++half) {
      bf16x8 af[2][2], bg[2][2];
      #pragma unroll
      for (int am = 0; am < 2; ++am)
        #pragma unroll
        for (int tt = 0; tt < 2; ++tt)
          af[am][tt] = *(const bf16x8*)(ldsc + curb + aoff[am] +
              ((((half * 2 + tt) << 5) + (hi << 4)) ^ swb));
      #pragma unroll
      for (int bn = 0; bn < 2; ++bn)
        #pragma unroll
        for (int tt = 0; tt < 2; ++tt)
          bg[bn][tt] = *(const bf16x8*)(ldsc + curb + boff[bn] +
              ((((half * 2 + tt) << 5) + (hi << 4)) ^ swb));
      #pragma unroll
      for (int am = 0; am < 2; ++am)
        #pragma unroll
        for (int bn = 0; bn < 2; ++bn)
          #pragma unroll
          for (int tt = 0; tt < 2; ++tt)
            acc[am][bn] = __builtin_amdgcn_mfma_f32_32x32x16_bf16(
                af[am][tt], bg[bn][tt], acc[am][bn], 0, 0, 0);
    }
    __builtin_amdgcn_s_setprio(0);
    asm volatile("s_waitcnt vmcnt(0)" ::: "memory");
    __builtin_amdgcn_s_barrier();
  }
  #pragma unroll
  for (int am = 0; am < 2; ++am) {
    const int mrowb = m0 + wm * 64 + am * 32 + (hi << 2);
    #pragma unroll
    for (int bn = 0; bn < 2; ++bn) {
      const int ncol = n0 + wn * 64 + bn * 32 + l31;
      #pragma unroll
      for (int qd = 0; qd < 4; ++qd)
        #pragma unroll
        for (int i = 0; i < 4; ++i)
          Cp[(size_t)(mrowb + 8 * qd + i) * N + ncol] = acc[am][bn][qd * 4 + i];
    }
  }
}

// ---------------------------------------------------------------------------
// Fused prep: blocks [0, 20480) = RMSNorm+RoPE (wave-per-row);
// blocks [20480, 20992) = V transpose + col-perm.  One launch, 256 threads.
__global__ __launch_bounds__(256)
void prep(const unsigned short* __restrict__ qkv,
          const float* __restrict__ cosb, const float* __restrict__ sinb,
          const float* __restrict__ qw, const float* __restrict__ kw,
          unsigned short* __restrict__ Qb, unsigned short* __restrict__ Kb,
          unsigned short* __restrict__ Vt) {
  __shared__ unsigned short tile[64][68];
  if (blockIdx.x < 20480) {
    const int wv = threadIdx.x >> 6, l = threadIdx.x & 63;
    const int rr = blockIdx.x * 4 + wv;
    const int hh = rr % 20, bt = rr / 20;
    const bool isq = hh < 16;
    const ushort2 u = *(const ushort2*)(qkv + (size_t)bt * 3072 + (hh << 7) + 2 * l);
    const float v0 = bf2f(u.x), v1 = bf2f(u.y);
    float ss = v0 * v0 + v1 * v1;
    #pragma unroll
    for (int off = 1; off < 64; off <<= 1) ss += __shfl_xor(ss, off);
    const float rms = rsqrtf(ss * (1.0f / 128.0f) + 1e-6f);
    const float* w = isq ? qw : kw;
    const float2 w2 = *(const float2*)(w + 2 * l);
    const float n0 = v0 * rms * w2.x, n1 = v1 * rms * w2.y;
    const float sx0 = __shfl_xor(n0, 32), sx1 = __shfl_xor(n1, 32);
    const float p0 = (l < 32) ? -sx0 : sx0;
    const float p1 = (l < 32) ? -sx1 : sx1;
    const float2 c2 = *(const float2*)(cosb + (size_t)bt * 128 + 2 * l);
    const float2 s2 = *(const float2*)(sinb + (size_t)bt * 128 + 2 * l);
    const float qsc = isq ? 0.08838834764831845f : 1.0f;
    ushort2 o;
    o.x = f2bf((n0 * c2.x + p0 * s2.x) * qsc);
    o.y = f2bf((n1 * c2.y + p1 * s2.y) * qsc);
    const int b = bt >> 11, t = bt & 2047;
    if (isq)
      *(ushort2*)(Qb + (((size_t)(b * 16 + hh) * 2048 + t) << 7) + 2 * l) = o;
    else
      *(ushort2*)(Kb + (((size_t)(b * 4 + (hh - 16)) * 2048 + t) << 7) + 2 * l) = o;
  } else {
    const int vb = blockIdx.x - 20480;      // 512 blocks: (bh 8, t0 32, d0 2)
    const int bh = vb >> 6, rest = vb & 63;
    const int b = bh >> 2, h = bh & 3;
    const int t0 = (rest >> 1) << 6, d0 = (rest & 1) << 6;
    const int tid = threadIdx.x;
    #pragma unroll
    for (int p = 0; p < 4; ++p) {
      const int idx = ((p << 8) + tid) << 2;
      const int r = idx >> 6, c = idx & 63;
      *(ushort4*)(&tile[r][c]) = *(const ushort4*)(
          qkv + (size_t)(b * 2048 + t0 + r) * 3072 + 2560 + (h << 7) + d0 + c);
    }
    __syncthreads();
    unsigned short* vbase = Vt + (size_t)((b * 4 + h) * 128 + d0) * 2048 + t0;
    #pragma unroll
    for (int p = 0; p < 4; ++p) {
      const int idx = ((p << 8) + tid) << 2;
      const int d = idx >> 6, tq = idx & 63;
      const int tin = (tq & 48) | ((tq & 8) >> 1) | ((tq & 4) << 1);
      ushort4 u;
      u.x = tile[tin + 0][d];
      u.y = tile[tin + 1][d];
      u.z = tile[tin + 2][d];
      u.w = tile[tin + 3][d];
      *(ushort4*)(vbase + ((size_t)d << 11) + tq) = u;
    }
  }
}

// ---------------------------------------------------------------------------
// Causal GQA flash attention (R20 exact, proven 63.0us): 32x32x16 MFMA,
// 8-wave even/odd kv-parity, adjacent tile pairing, balanced p relabel,
// 16-slot K swizzle, 2-barrier 2-block/CU.
__global__ __launch_bounds__(512)
void attn_fwd(const unsigned short* __restrict__ Qb,  // (B,H,T,D), pre-scaled
              const unsigned short* __restrict__ Kb,  // (B,KH,T,D)
              const unsigned short* __restrict__ Vt,  // (B,KH,D,T'), col-permuted
              unsigned short* __restrict__ Y) {       // (B,T,H,D)
  __shared__ __align__(16) char L[65536];  // [g][K 16KB | V 16KB]
  const int bh = blockIdx.x;
  const int b = bh >> 4, h = bh & 15, hk = h >> 2;
  const int py = blockIdx.y;
  const int p = (py < 8) ? py : 23 - py;   // balanced relabel (bijective 0..15)
  const int tid = threadIdx.x;
  const int lane = tid & 63, wid = tid >> 6;
  const int g = wid >> 2;            // kv parity group
  const int wid2 = wid & 3;
  const int j = wid2 >> 1;           // tile slot
  const int qt = (p << 1) + j;       // adjacent pairing
  const int sub = (wid2 & 1) << 5;   // row half within tile
  const int l31 = lane & 31, hi = lane >> 5;
  const int swbK = (lane & 15) << 4;   // K: 16 slots (256B rows)
  const int swbV = (lane & 7) << 4;    // V: 8 slots (128B rows)
  char* KsC = L + g * 32768;
  char* VsC = KsC + 16384;
  const unsigned short* Kp = Kb + (size_t)(b * 4 + hk) * 2048 * 128;
  const unsigned short* Vp = Vt + (size_t)(b * 4 + hk) * 128 * 2048;
  const int qg = qt * 64 + sub + l31;   // this lane's q-row
  const unsigned short* Qp = Qb + (size_t)((b * 16 + h) * 2048 + qg) * 128;
  bf16x8 aq[8];
  #pragma unroll
  for (int ks = 0; ks < 8; ++ks)
    aq[ks] = *(const bf16x8*)(Qp + (ks << 4) + (hi << 3));
  float m_i = -1e30f, l_i = 0.f;
  f32x16 acc[4] = {};   // dblk 0..3; d = 32*dblk + (r&3)+8*(r>>2)+4*hi
  const int kr_in = (lane >> 4), kcb = (lane & 15) << 4;   // K chunk: 4 rows x 256B
  const int vr_in = (lane >> 3), vcb = (lane & 7) << 4;    // V chunk: 8 rows x 128B
  const int nkb = (p << 1) + 2;       // stage exactly tiles 0..2p+1
  const int nit = (nkb + 1) >> 1;     // = p+1

  for (int it = 0; it < nit; ++it) {
    const int kb = 2 * it + g;
    const bool act = kb < nkb;          // wave-uniform (always true here)
    if (act) {
      const int k0 = kb << 6;
      #pragma unroll
      for (int i = 0; i < 4; ++i) {
        const int c = (wid2 << 2) + i;
        { const int r = (c << 2) + kr_in;
          const int sw = kcb ^ ((r & 15) << 4);   // 16-slot involution
          gl_lds16(Kp + (size_t)(k0 + r) * 128 + (sw >> 1), KsC + (c << 10)); }
        { const int r = (c << 3) + vr_in;
          const int sw = vcb ^ ((r & 7) << 4);
          gl_lds16(Vp + (size_t)r * 2048 + k0 + (sw >> 1), VsC + (c << 10)); }
      }
    }
    __syncthreads();
    if (act && kb <= qt) {
      const int k0 = kb << 6;
      f32x16 s[2] = {};
      __builtin_amdgcn_s_setprio(1);
      #pragma unroll
      for (int sblk = 0; sblk < 2; ++sblk) {
        const int row = (sblk << 5) + l31;
        #pragma unroll
        for (int ks = 0; ks < 8; ++ks) {
          const bf16x8 bk = *(const bf16x8*)(
              KsC + (row << 8) + (((ks << 5) + (hi << 4)) ^ swbK));
          s[sblk] = __builtin_amdgcn_mfma_f32_32x32x16_bf16(bk, aq[ks], s[sblk], 0, 0, 0);
        }
      }
      __builtin_amdgcn_s_setprio(0);
      if (kb == qt) {   // causal mask, diag block only
        #pragma unroll
        for (int sblk = 0; sblk < 2; ++sblk)
          #pragma unroll
          for (int r = 0; r < 16; ++r) {
            const int kv = k0 + (sblk << 5) + (r & 3) + ((r >> 2) << 3) + (hi << 2);
            if (kv > qg) s[sblk][r] = -1e30f;
          }
      }
      float mx = s[0][0];
      #pragma unroll
      for (int sblk = 0; sblk < 2; ++sblk)
        #pragma unroll
        for (int r = 0; r < 16; ++r) mx = fmaxf(mx, s[sblk][r]);
      mx = fmaxf(mx, __shfl_xor(mx, 32));
      if (!__all(mx <= m_i + 8.0f)) {   // defer-max (THR=8)
        const float mn = fmaxf(m_i, mx);
        const float r = __expf(m_i - mn);
        m_i = mn;
        l_i *= r;
        #pragma unroll
        for (int d = 0; d < 4; ++d)
          #pragma unroll
          for (int i = 0; i < 16; ++i) acc[d][i] *= r;
      }
      float se = 0.f;
      unsigned pk[16];
      #pragma unroll
      for (int t2 = 0; t2 < 16; ++t2) {
        const int f0 = 2 * t2, f1 = 2 * t2 + 1;
        const float e0 = __expf(s[f0 >> 4][f0 & 15] - m_i);
        const float e1 = __expf(s[f1 >> 4][f1 & 15] - m_i);
        se += e0 + e1;
        pk[t2] = cvtpk_bf16(e0, e1);
      }
      se += __shfl_xor(se, 32);
      l_i += se;
      __builtin_amdgcn_s_setprio(1);
      #pragma unroll
      for (int dblk = 0; dblk < 4; ++dblk) {
        const int row = (dblk << 5) + l31;
        #pragma unroll
        for (int cp = 0; cp < 4; ++cp) {
          const bf16x8 va = *(const bf16x8*)(
              VsC + (row << 7) + (((cp << 5) + (hi << 4)) ^ swbV));
          union { unsigned u[4]; bf16x8 v; } pb;
          pb.u[0] = pk[cp * 4 + 0]; pb.u[1] = pk[cp * 4 + 1];
          pb.u[2] = pk[cp * 4 + 2]; pb.u[3] = pk[cp * 4 + 3];
          acc[dblk] = __builtin_amdgcn_mfma_f32_32x32x16_bf16(va, pb.v, acc[dblk], 0, 0, 0);
        }
      }
      __builtin_amdgcn_s_setprio(0);
    }
    __syncthreads();
  }

  // parity combine: round jj — g=1 waves of tile jj dump, g=0 merge+write.
  float* cb = (float*)L;
  #pragma unroll
  for (int jj = 0; jj < 2; ++jj) {
    const int base = (((wid2 & 1) << 6) + lane) * 66;
    if (g == 1 && j == jj) {
      #pragma unroll
      for (int d = 0; d < 4; ++d)
        #pragma unroll
        for (int i = 0; i < 16; ++i) cb[base + d * 16 + i] = acc[d][i];
      cb[base + 64] = m_i;
      cb[base + 65] = l_i;
    }
    __syncthreads();
    if (g == 0 && j == jj) {
      const float m1 = cb[base + 64], l1v = cb[base + 65];
      const float m = fmaxf(m_i, m1);
      const float e0 = __expf(m_i - m), e1 = __expf(m1 - m);
      const float inv = 1.0f / (l_i * e0 + l1v * e1);
      unsigned short* Yp = Y + (((size_t)b * 2048 + qg) * 16 + h) * 128;
      #pragma unroll
      for (int dblk = 0; dblk < 4; ++dblk) {
        #pragma unroll
        for (int qd = 0; qd < 4; ++qd) {
          ushort4 o;
          o.x = f2bf((acc[dblk][qd * 4 + 0] * e0 + cb[base + dblk * 16 + qd * 4 + 0] * e1) * inv);
          o.y = f2bf((acc[dblk][qd * 4 + 1] * e0 + cb[base + dblk * 16 + qd * 4 + 1] * e1) * inv);
          o.z = f2bf((acc[dblk][qd * 4 + 2] * e0 + cb[base + dblk * 16 + qd * 4 + 2] * e1) * inv);
          o.w = f2bf((acc[dblk][qd * 4 + 3] * e0 + cb[base + dblk * 16 + qd * 4 + 3] * e1) * inv);
          *(ushort4*)(Yp + (dblk << 5) + (qd << 3) + (hi << 2)) = o;
        }
      }
    }
    __syncthreads();
  }
}

// ---------------------------------------------------------------------------
extern "C" void kernel_launch(void* const* d_in, const int* in_sizes, int n_in,
                              void* d_out, int out_size, void* d_ws, size_t ws_size,
                              hipStream_t stream) {
  const float* x    = (const float*)d_in[0];
  const float* cosb = (const float*)d_in[1];
  const float* sinb = (const float*)d_in[2];
  const float* Wq   = (const float*)d_in[3];
  const float* Wk   = (const float*)d_in[4];
  const float* Wv   = (const float*)d_in[5];
  const float* Wo   = (const float*)d_in[6];
  const float* qw   = (const float*)d_in[7];
  const float* kw   = (const float*)d_in[8];
  char* ws = (char*)d_ws;
  unsigned short* xb   = (unsigned short*)(ws);                       // 16MB x bf16, later reused as Y
  unsigned short* Wcat = (unsigned short*)(ws + (16ull << 20));       // 12MB [Wq;Wk;Wv] bf16
  unsigned short* Wob  = (unsigned short*)(ws + (28ull << 20));       // 8MB Wo bf16
  unsigned short* qkv  = (unsigned short*)(ws + (36ull << 20));       // 24MB (4096,3072) bf16
  unsigned short* Qb   = (unsigned short*)(ws + (60ull << 20));       // 16MB (B,H,T,D)
  unsigned short* Kb   = (unsigned short*)(ws + (76ull << 20));       // 4MB  (B,KH,T,D)
  unsigned short* Vt   = (unsigned short*)(ws + (80ull << 20));       // 4MB  (B,KH,D,T'), col-permuted

  // all input casts in one launch
  cvt_all<<<2048, 256, 0, stream>>>(x, Wq, Wk, Wv, Wo, xb, Wcat, Wob);

  // qkv = x @ [Wq;Wk;Wv]^T   (M=4096, N=3072, K=2048): 32x8 = 256 blocks = 1/CU
  gemm384<<<256, 512, 0, stream>>>(xb, Wcat, qkv, 4096, 3072, 2048);
  // RMSNorm+RoPE (20480 blocks) + V-transpose (512 blocks) in one launch
  prep<<<20992, 256, 0, stream>>>(qkv, cosb, sinb, qw, kw, Qb, Kb, Vt);
  // attention -> Y (reuses xb); balanced p relabel, even/odd kv parity
  attn_fwd<<<dim3(32, 16), 512, 0, stream>>>(Qb, Kb, Vt, xb);
  // out = Y @ Wo^T  (M=4096, N=2048, K=2048): 32x8 = 256 blocks = 1/CU
  gemm128n<<<256, 512, 0, stream>>>(xb, Wob, (float*)d_out, 4096, 2048, 2048);
}